// Round 2
// baseline (24983.214 us; speedup 1.0000x reference)
//
#include <hip/hip_runtime.h>
#include <hip/hip_bf16.h>

typedef _Float16 f16x8 __attribute__((ext_vector_type(8)));
typedef float f32x4 __attribute__((ext_vector_type(4)));

#define B_  128
#define T_  1024
#define H_  512
#define P_  32      // chunk-workers per batch group
#define HC_ 16      // h-columns per worker
#define MB_ 16      // batch elements per group
#define NG_ 8       // batch groups (grp = bid&7 -> all same-XCD)

// ws layout (bytes)
#define WS_HEXHI  0ull                       // f16 hexhi[2][NG][MB][H] = 262144
#define WS_HEXLO  262144ull
#define WS_CNT    524288ull                  // unsigned cnt[NG] (pad 256)
#define WS_ZERO   524544ull                  // zero region = hexhi+hexlo+cnt
#define WS_HLAST  524544ull                  // float hlast[B][H] = 262144
#define WS_H1HI   786688ull                  // f16 h1hi[B][T][H] = 134217728
#define WS_H1LO   (786688ull + 134217728ull)
#define WS_NEED_SMALL (786688ull + 134217728ull)          // hi plane only
#define WS_NEED_FULL  (786688ull + 2ull * 134217728ull)   // hi+lo planes

// One workgroup = 1 wave, owns HC_=16 hidden cols x MB_=16 batches.
// LDS plane 0: R_hi frags. LDS plane 1: L1 -> R_lo frags, L2 -> W_hi frags.
// Frag layout (verified r1): B-frag (q,kt): lane l holds col=l&15 (gate row
// q*512+p*16+(l&15)), k = kt*32+(l>>4)*8 + 0..7.
template<int LAYER>
__global__ __launch_bounds__(64)
void slstm_kernel(const float* __restrict__ xin,       // L1: x (B,T,3)
                  const _Float16* __restrict__ h1ihi,  // L2: h1 hi plane
                  const _Float16* __restrict__ h1ilo,  // L2: h1 lo plane
                  const float* __restrict__ Wg,        // W0 (2048,3) / W1 (2048,512)
                  const float* __restrict__ Rg,        // R (2048,512)
                  const float* __restrict__ bg,        // b (2048)
                  _Float16* __restrict__ hexhi,        // [2][NG][MB][H]
                  _Float16* __restrict__ hexlo,
                  unsigned* __restrict__ cnt,          // [NG]
                  _Float16* __restrict__ h1ohi,        // L1 out hi plane
                  _Float16* __restrict__ h1olo,        // L1 out lo plane
                  float* __restrict__ hlast,           // L2: (B,H) fp32
                  int useH1Lo)
{
    constexpr int LDSH = 4 * 16 * 64 * 8;              // 32768 f16 = 64 KB/plane
    __shared__ _Float16 lds[2 * LDSH];

    const int lane = threadIdx.x;
    const int l15  = lane & 15;
    const int l4   = lane >> 4;
    const int kg8  = l4 * 8;
    const int bid  = blockIdx.x;
    const int grp  = bid & 7;      // same grp -> same XCD (round-robin dispatch)
    const int p    = bid >> 3;     // 0..31
    const int b0   = grp * MB_;

    // ---- stage weight chunks into LDS (frag-major, f16) ----
    for (int q = 0; q < 4; ++q) {
        const int grow = q * 512 + p * HC_ + l15;
        const float* rsrc = Rg + (size_t)grow * H_ + kg8;
        for (int kt = 0; kt < 16; ++kt) {
            const float* s = rsrc + kt * 32;
            _Float16* dhi = &lds[((q * 16 + kt) * 64 + lane) * 8];
            _Float16* dlo = dhi + LDSH;
            if (LAYER == 1) {
                #pragma unroll
                for (int j = 0; j < 8; ++j) {
                    float v = s[j];
                    _Float16 h = (_Float16)v;
                    dhi[j] = h;
                    dlo[j] = (_Float16)(v - (float)h);  // R_lo
                }
            } else {
                const float* ws2 = Wg + (size_t)grow * H_ + kt * 32 + kg8;
                #pragma unroll
                for (int j = 0; j < 8; ++j) {
                    dhi[j] = (_Float16)s[j];            // R_hi
                    dlo[j] = (_Float16)ws2[j];          // W_hi
                }
            }
        }
    }
    __syncthreads();

    float w0v[4][3];
    if (LAYER == 1) {
        #pragma unroll
        for (int q = 0; q < 4; ++q)
            #pragma unroll
            for (int d = 0; d < 3; ++d)
                w0v[q][d] = Wg[(size_t)(q * 512 + p * HC_ + l15) * 3 + d];
    }

    float bq[4];
    #pragma unroll
    for (int q = 0; q < 4; ++q) bq[q] = bg[q * 512 + p * HC_ + l15];

    float cS[4] = {0,0,0,0}, nS[4] = {0,0,0,0}, mS[4] = {0,0,0,0};
    unsigned* myCnt = cnt + grp;

    for (int t = 0; t < T_; ++t) {
        // ---- accumulators ----
        f32x4 acc[4];
        #pragma unroll
        for (int q = 0; q < 4; ++q) { f32x4 a = {bq[q], bq[q], bq[q], bq[q]}; acc[q] = a; }

        // ---- feed-forward path: fully independent of h_t, runs pre-barrier ----
        if (LAYER == 2) {
            f16x8 aXhi[16];
            const _Float16* srcH = h1ihi + ((size_t)(b0 + l15) * T_ + t) * H_ + kg8;
            #pragma unroll
            for (int kt = 0; kt < 16; ++kt)
                aXhi[kt] = *reinterpret_cast<const f16x8*>(srcH + kt * 32);
            if (useH1Lo) {
                f16x8 aXlo[16];
                const _Float16* srcL = h1ilo + ((size_t)(b0 + l15) * T_ + t) * H_ + kg8;
                #pragma unroll
                for (int kt = 0; kt < 16; ++kt)
                    aXlo[kt] = *reinterpret_cast<const f16x8*>(srcL + kt * 32);
                #pragma unroll
                for (int kt = 0; kt < 16; ++kt)
                    #pragma unroll
                    for (int q = 0; q < 4; ++q) {
                        f16x8 w = *reinterpret_cast<const f16x8*>(&lds[LDSH + ((q * 16 + kt) * 64 + lane) * 8]);
                        acc[q] = __builtin_amdgcn_mfma_f32_16x16x32_f16(aXhi[kt], w, acc[q], 0, 0, 0);
                        acc[q] = __builtin_amdgcn_mfma_f32_16x16x32_f16(aXlo[kt], w, acc[q], 0, 0, 0);
                    }
            } else {
                #pragma unroll
                for (int kt = 0; kt < 16; ++kt)
                    #pragma unroll
                    for (int q = 0; q < 4; ++q) {
                        f16x8 w = *reinterpret_cast<const f16x8*>(&lds[LDSH + ((q * 16 + kt) * 64 + lane) * 8]);
                        acc[q] = __builtin_amdgcn_mfma_f32_16x16x32_f16(aXhi[kt], w, acc[q], 0, 0, 0);
                    }
            }
        } else {
            float xv[4][3];
            const float* xp = xin + ((size_t)(b0 + l4 * 4) * T_ + t) * 3;
            #pragma unroll
            for (int r = 0; r < 4; ++r)
                #pragma unroll
                for (int d = 0; d < 3; ++d)
                    xv[r][d] = xp[(size_t)r * T_ * 3 + d];
            #pragma unroll
            for (int q = 0; q < 4; ++q)
                #pragma unroll
                for (int r = 0; r < 4; ++r)
                    acc[q][r] += w0v[q][0]*xv[r][0] + w0v[q][1]*xv[r][1] + w0v[q][2]*xv[r][2];
        }

        // ---- spin: wait until all P_ members published h_t ----
        if (t > 0) {
            while (__hip_atomic_load(myCnt, __ATOMIC_ACQUIRE, __HIP_MEMORY_SCOPE_AGENT)
                   < (unsigned)(P_ * t)) {
                __builtin_amdgcn_s_sleep(1);
            }
        }

        // ---- recurrent path: h_t hi/lo A-frags, R_hi (+R_lo for L1) ----
        f16x8 aHhi[16], aHlo[16];
        {
            const size_t hb = (((size_t)(t & 1) * NG_ + grp) * MB_ + l15) * H_ + kg8;
            #pragma unroll
            for (int kt = 0; kt < 16; ++kt) {
                aHhi[kt] = *reinterpret_cast<const f16x8*>(hexhi + hb + kt * 32);
                aHlo[kt] = *reinterpret_cast<const f16x8*>(hexlo + hb + kt * 32);
            }
        }
        #pragma unroll
        for (int kt = 0; kt < 16; ++kt)
            #pragma unroll
            for (int q = 0; q < 4; ++q) {
                f16x8 rhi = *reinterpret_cast<const f16x8*>(&lds[((q * 16 + kt) * 64 + lane) * 8]);
                acc[q] = __builtin_amdgcn_mfma_f32_16x16x32_f16(aHhi[kt], rhi, acc[q], 0, 0, 0);
                acc[q] = __builtin_amdgcn_mfma_f32_16x16x32_f16(aHlo[kt], rhi, acc[q], 0, 0, 0);
            }
        if (LAYER == 1) {
            #pragma unroll
            for (int kt = 0; kt < 16; ++kt)
                #pragma unroll
                for (int q = 0; q < 4; ++q) {
                    f16x8 rlo = *reinterpret_cast<const f16x8*>(&lds[LDSH + ((q * 16 + kt) * 64 + lane) * 8]);
                    acc[q] = __builtin_amdgcn_mfma_f32_16x16x32_f16(aHhi[kt], rlo, acc[q], 0, 0, 0);
                }
        }

        // ---- sLSTM gates (fp32; states private to this wave) ----
        float hn[4];
        #pragma unroll
        for (int r = 0; r < 4; ++r) {
            float iv = acc[0][r], fv = acc[1][r], zv = acc[2][r], ov = acc[3][r];
            float fm = fv + mS[r];
            float mn = fmaxf(fm, iv);
            float ig = __expf(iv - mn);
            float fg = __expf(fm - mn);
            float zc = fminf(fmaxf(zv, -15.f), 15.f);
            float e2 = __expf(2.f * zc);
            float th = (e2 - 1.f) / (e2 + 1.f);
            cS[r] = fg * cS[r] + ig * th;
            nS[r] = fg * nS[r] + ig;
            mS[r] = mn;
            float sg = 1.f / (1.f + __expf(-ov));
            hn[r] = sg * cS[r] / fmaxf(nS[r], 1e-6f);
        }

        // ---- publish h_{t+1} chunk as hi/lo planes ----
        {
            const size_t wb = (((size_t)((t + 1) & 1) * NG_ + grp) * MB_ + l4 * 4) * H_ + p * HC_ + l15;
            #pragma unroll
            for (int r = 0; r < 4; ++r) {
                float v = hn[r];
                _Float16 hi = (_Float16)v;
                _Float16 lo = (_Float16)(v - (float)hi);
                hexhi[wb + (size_t)r * H_] = hi;
                hexlo[wb + (size_t)r * H_] = lo;
            }
        }
        if (LAYER == 1) {
            const size_t ob = ((size_t)(b0 + l4 * 4) * T_ + t) * H_ + p * HC_ + l15;
            #pragma unroll
            for (int r = 0; r < 4; ++r) {
                float v = hn[r];
                _Float16 hi = (_Float16)v;
                h1ohi[ob + (size_t)r * T_ * H_] = hi;
                if (useH1Lo)
                    h1olo[ob + (size_t)r * T_ * H_] = (_Float16)(v - (float)hi);
            }
        }
        if (LAYER == 2 && t == T_ - 1) {
            float* hl = hlast + (size_t)(b0 + l4 * 4) * H_ + p * HC_ + l15;
            #pragma unroll
            for (int r = 0; r < 4; ++r) hl[(size_t)r * H_] = hn[r];
        }

        if (lane == 0)
            __hip_atomic_fetch_add(myCnt, 1u, __ATOMIC_RELEASE, __HIP_MEMORY_SCOPE_AGENT);
    }
}

#define OUT_ 26
__global__ __launch_bounds__(64)
void fc_kernel(const float* __restrict__ hlast, const float* __restrict__ fcw,
               const float* __restrict__ fcb, float* __restrict__ out)
{
    int b = blockIdx.x, o = threadIdx.x;
    if (o < OUT_) {
        const float4* hv = reinterpret_cast<const float4*>(hlast + (size_t)b * H_);
        const float4* wv = reinterpret_cast<const float4*>(fcw + (size_t)o * H_);
        float s = fcb[o];
        #pragma unroll 4
        for (int k = 0; k < H_ / 4; ++k) {
            float4 h4 = hv[k], w4 = wv[k];
            s += h4.x * w4.x + h4.y * w4.y + h4.z * w4.z + h4.w * w4.w;
        }
        out[(size_t)b * OUT_ + o] = s;
    }
}

extern "C" void kernel_launch(void* const* d_in, const int* in_sizes, int n_in,
                              void* d_out, int out_size, void* d_ws, size_t ws_size,
                              hipStream_t stream) {
    const float* x   = (const float*)d_in[0];
    const float* W0  = (const float*)d_in[1];
    const float* R0  = (const float*)d_in[2];
    const float* b0  = (const float*)d_in[3];
    const float* W1  = (const float*)d_in[4];
    const float* R1  = (const float*)d_in[5];
    const float* b1  = (const float*)d_in[6];
    const float* fcw = (const float*)d_in[7];
    const float* fcb = (const float*)d_in[8];
    float* out = (float*)d_out;

    if (ws_size < WS_NEED_SMALL) return;  // fail-visible rather than corrupt
    const int useH1Lo = (ws_size >= WS_NEED_FULL) ? 1 : 0;

    char* ws = (char*)d_ws;
    _Float16* hexhi = (_Float16*)(ws + WS_HEXHI);
    _Float16* hexlo = (_Float16*)(ws + WS_HEXLO);
    unsigned* cnt   = (unsigned*)(ws + WS_CNT);
    float*    hlast = (float*)(ws + WS_HLAST);
    _Float16* h1hi  = (_Float16*)(ws + WS_H1HI);
    _Float16* h1lo  = (_Float16*)(ws + WS_H1LO);

    hipMemsetAsync(ws, 0, WS_ZERO, stream);
    slstm_kernel<1><<<NG_ * P_, 64, 0, stream>>>(x, nullptr, nullptr, W0, R0, b0,
                                                 hexhi, hexlo, cnt, h1hi, h1lo, nullptr, useH1Lo);
    hipMemsetAsync(ws, 0, WS_ZERO, stream);
    slstm_kernel<2><<<NG_ * P_, 64, 0, stream>>>(nullptr, h1hi, h1lo, W1, R1, b1,
                                                 hexhi, hexlo, cnt, nullptr, nullptr, hlast, useH1Lo);
    fc_kernel<<<B_, 64, 0, stream>>>(hlast, fcw, fcb, out);
}

// Round 3
// 17571.043 us; speedup vs baseline: 1.4218x; 1.4218x over previous
//
#include <hip/hip_runtime.h>
#include <hip/hip_bf16.h>

typedef _Float16 f16x8 __attribute__((ext_vector_type(8)));
typedef float f32x4 __attribute__((ext_vector_type(4)));

#define B_   128
#define T_   1024
#define H_   512
#define P_   32      // chunk-workers per clique (16 h-cols each)
#define HC_  16
#define MB_  32      // batch elements per clique (2 M-tiles of 16)
#define NC_  8       // cliques: 0-3 = layer1 groups 0-3, 4-7 = layer2 groups 0-3

// ws layout (bytes)
#define WS_HEXHI   0ull                         // f16 [2][NC][MB][H] = 524288
#define WS_HEXLO   524288ull                    // f16 [2][NC][MB][H] = 524288
#define WS_FLAGS   1048576ull                   // u32 flags[NC][32][16] (64B-strided) = 16384
#define WS_ZERO    1064960ull                   // zero region: hex + flags
#define WS_HLAST   1064960ull                   // float [B][H] = 262144
#define WS_H1HI    1327104ull                   // f16 [B][T][H] = 134217728
#define WS_H1LO    (1327104ull + 134217728ull)
#define WS_NEED_SMALL (1327104ull + 134217728ull)
#define WS_NEED_FULL  (1327104ull + 2ull * 134217728ull)

#define MFMA(a, b, c) __builtin_amdgcn_mfma_f32_16x16x32_f16((a), (b), (c), 0, 0, 0)

__device__ __forceinline__ void pollflags(unsigned* flags, int cl, unsigned tgt, int lane) {
    unsigned* fp = flags + ((size_t)cl * 32 + (lane & 31)) * 16;
    for (;;) {
        unsigned v = __hip_atomic_load(fp, __ATOMIC_RELAXED, __HIP_MEMORY_SCOPE_AGENT);
        if (__ballot(v >= tgt) == ~0ull) break;
        __builtin_amdgcn_s_sleep(1);
    }
    // one acquire round: synchronizes-with every producer's release store
    (void)__hip_atomic_load(fp, __ATOMIC_ACQUIRE, __HIP_MEMORY_SCOPE_AGENT);
}

// 256 blocks x 64 threads (1 wave), 128KB LDS -> exactly 1 block/CU, all resident.
// Clique c = bid&7 (one XCD under round-robin dispatch): c<4 -> layer1 batch
// group c; c>=4 -> layer2 batch group c-4. p = bid>>3 owns h-cols [p*16, p*16+16).
// LDS plane0 = R_hi B-frags; plane1 = L1: R_lo, L2: W1_hi.
__global__ __launch_bounds__(64, 1)
void fused_slstm(const float* __restrict__ x,
                 const float* __restrict__ W0, const float* __restrict__ R0,
                 const float* __restrict__ b0v,
                 const float* __restrict__ W1, const float* __restrict__ R1,
                 const float* __restrict__ b1v,
                 _Float16* __restrict__ hexhi, _Float16* __restrict__ hexlo,
                 unsigned* __restrict__ flags,
                 _Float16* __restrict__ h1hi, _Float16* __restrict__ h1lo,
                 float* __restrict__ hlast, int useH1Lo)
{
    constexpr int LDSH = 4 * 16 * 64 * 8;   // 32768 f16 = 64 KB per plane
    __shared__ _Float16 lds[2 * LDSH];

    const int lane = threadIdx.x;
    const int l15  = lane & 15;
    const int l4   = lane >> 4;
    const int kg8  = l4 * 8;
    const int bid  = blockIdx.x;
    const int c    = bid & 7;
    const int p    = bid >> 3;
    const bool isL2 = (c >= 4);
    const int g    = c & 3;
    const int b0g  = g * MB_;

    const float* Rg = isL2 ? R1 : R0;
    const float* bg = isL2 ? b1v : b0v;

    // ---- stage weight chunks into LDS (frag-major f16) ----
    for (int q = 0; q < 4; ++q) {
        const int grow = q * H_ + p * HC_ + l15;          // gate row (4H major)
        const float* rsrc = Rg + (size_t)grow * H_ + kg8;
        for (int kt = 0; kt < 16; ++kt) {
            const float* s = rsrc + kt * 32;
            _Float16* dhi = &lds[((q * 16 + kt) * 64 + lane) * 8];
            _Float16* dlo = dhi + LDSH;
            if (!isL2) {
                #pragma unroll
                for (int j = 0; j < 8; ++j) {
                    float v = s[j];
                    _Float16 h = (_Float16)v;
                    dhi[j] = h;
                    dlo[j] = (_Float16)(v - (float)h);    // R0_lo
                }
            } else {
                const float* ws2 = W1 + (size_t)grow * H_ + kt * 32 + kg8;
                #pragma unroll
                for (int j = 0; j < 8; ++j) {
                    dhi[j] = (_Float16)s[j];              // R1_hi
                    dlo[j] = (_Float16)ws2[j];            // W1_hi
                }
            }
        }
    }
    __syncthreads();

    float w0v[4][3];
    if (!isL2) {
        #pragma unroll
        for (int q = 0; q < 4; ++q)
            #pragma unroll
            for (int d = 0; d < 3; ++d)
                w0v[q][d] = W0[(size_t)(q * H_ + p * HC_ + l15) * 3 + d];
    }
    float bq[4];
    #pragma unroll
    for (int q = 0; q < 4; ++q) bq[q] = bg[q * H_ + p * HC_ + l15];

    float cS[2][4], nS[2][4], mS[2][4];
    #pragma unroll
    for (int mt = 0; mt < 2; ++mt)
        #pragma unroll
        for (int r = 0; r < 4; ++r) { cS[mt][r] = 0.f; nS[mt][r] = 0.f; mS[mt][r] = 0.f; }

    unsigned* myFlag = flags + ((size_t)c * 32 + p) * 16;

    for (int t = 0; t < T_; ++t) {
        f32x4 acc[2][4];
        #pragma unroll
        for (int mt = 0; mt < 2; ++mt)
            #pragma unroll
            for (int q = 0; q < 4; ++q) { f32x4 a = {bq[q], bq[q], bq[q], bq[q]}; acc[mt][q] = a; }

        // ================= feed-forward path =================
        if (!isL2) {
            float xv[2][4][3];
            #pragma unroll
            for (int mt = 0; mt < 2; ++mt)
                #pragma unroll
                for (int r = 0; r < 4; ++r) {
                    const float* xp = x + ((size_t)(b0g + mt * 16 + l4 * 4 + r) * T_ + t) * 3;
                    xv[mt][r][0] = xp[0]; xv[mt][r][1] = xp[1]; xv[mt][r][2] = xp[2];
                }
            #pragma unroll
            for (int mt = 0; mt < 2; ++mt)
                #pragma unroll
                for (int q = 0; q < 4; ++q)
                    #pragma unroll
                    for (int r = 0; r < 4; ++r)
                        acc[mt][q][r] += w0v[q][0]*xv[mt][r][0] + w0v[q][1]*xv[mt][r][1]
                                       + w0v[q][2]*xv[mt][r][2];
        } else {
            // wait for layer-1 group g to publish h1[t] (flag = t+1)
            pollflags(flags, g, (unsigned)(t + 1), lane);
            const size_t h1b0 = ((size_t)(b0g + l15) * T_ + t) * H_ + kg8;
            const size_t h1b1 = ((size_t)(b0g + 16 + l15) * T_ + t) * H_ + kg8;
            if (useH1Lo) {
                #pragma unroll
                for (int kt = 0; kt < 16; ++kt) {
                    f16x8 a0h = *(const f16x8*)(h1hi + h1b0 + kt * 32);
                    f16x8 a1h = *(const f16x8*)(h1hi + h1b1 + kt * 32);
                    f16x8 a0l = *(const f16x8*)(h1lo + h1b0 + kt * 32);
                    f16x8 a1l = *(const f16x8*)(h1lo + h1b1 + kt * 32);
                    f16x8 w[4];
                    #pragma unroll
                    for (int q = 0; q < 4; ++q)
                        w[q] = *(const f16x8*)&lds[LDSH + ((q * 16 + kt) * 64 + lane) * 8];
                    #pragma unroll
                    for (int q = 0; q < 4; ++q) { acc[0][q] = MFMA(a0h, w[q], acc[0][q]);
                                                  acc[1][q] = MFMA(a1h, w[q], acc[1][q]); }
                    #pragma unroll
                    for (int q = 0; q < 4; ++q) { acc[0][q] = MFMA(a0l, w[q], acc[0][q]);
                                                  acc[1][q] = MFMA(a1l, w[q], acc[1][q]); }
                }
            } else {
                #pragma unroll
                for (int kt = 0; kt < 16; ++kt) {
                    f16x8 a0h = *(const f16x8*)(h1hi + h1b0 + kt * 32);
                    f16x8 a1h = *(const f16x8*)(h1hi + h1b1 + kt * 32);
                    f16x8 w[4];
                    #pragma unroll
                    for (int q = 0; q < 4; ++q)
                        w[q] = *(const f16x8*)&lds[LDSH + ((q * 16 + kt) * 64 + lane) * 8];
                    #pragma unroll
                    for (int q = 0; q < 4; ++q) { acc[0][q] = MFMA(a0h, w[q], acc[0][q]);
                                                  acc[1][q] = MFMA(a1h, w[q], acc[1][q]); }
                }
            }
        }

        // ================= recurrent path =================
        if (t > 0) pollflags(flags, c, (unsigned)t, lane);

        {
            const size_t hb0 = ((size_t)(t & 1) * NC_ + c) * (MB_ * H_) + (size_t)l15 * H_ + kg8;
            const size_t hb1 = hb0 + (size_t)16 * H_;
            #pragma unroll
            for (int kt = 0; kt < 16; ++kt) {
                f16x8 a0h = *(const f16x8*)(hexhi + hb0 + kt * 32);
                f16x8 a1h = *(const f16x8*)(hexhi + hb1 + kt * 32);
                f16x8 a0l = *(const f16x8*)(hexlo + hb0 + kt * 32);
                f16x8 a1l = *(const f16x8*)(hexlo + hb1 + kt * 32);
                f16x8 rh[4];
                #pragma unroll
                for (int q = 0; q < 4; ++q)
                    rh[q] = *(const f16x8*)&lds[((q * 16 + kt) * 64 + lane) * 8];
                #pragma unroll
                for (int q = 0; q < 4; ++q) { acc[0][q] = MFMA(a0h, rh[q], acc[0][q]);
                                              acc[1][q] = MFMA(a1h, rh[q], acc[1][q]); }
                #pragma unroll
                for (int q = 0; q < 4; ++q) { acc[0][q] = MFMA(a0l, rh[q], acc[0][q]);
                                              acc[1][q] = MFMA(a1l, rh[q], acc[1][q]); }
                if (!isL2) {
                    f16x8 rl[4];
                    #pragma unroll
                    for (int q = 0; q < 4; ++q)
                        rl[q] = *(const f16x8*)&lds[LDSH + ((q * 16 + kt) * 64 + lane) * 8];
                    #pragma unroll
                    for (int q = 0; q < 4; ++q) { acc[0][q] = MFMA(a0h, rl[q], acc[0][q]);
                                                  acc[1][q] = MFMA(a1h, rl[q], acc[1][q]); }
                }
            }
        }

        // ================= gates + publish =================
        #pragma unroll
        for (int mt = 0; mt < 2; ++mt) {
            float hn[4];
            #pragma unroll
            for (int r = 0; r < 4; ++r) {
                float iv = acc[mt][0][r], fv = acc[mt][1][r];
                float zv = acc[mt][2][r], ov = acc[mt][3][r];
                float fm = fv + mS[mt][r];
                float mn = fmaxf(fm, iv);
                float ig = __expf(iv - mn);
                float fg = __expf(fm - mn);
                float zc = fminf(fmaxf(zv, -15.f), 15.f);
                float e2 = __expf(2.f * zc);
                float th = (e2 - 1.f) / (e2 + 1.f);
                cS[mt][r] = fg * cS[mt][r] + ig * th;
                nS[mt][r] = fg * nS[mt][r] + ig;
                mS[mt][r] = mn;
                float sg = 1.f / (1.f + __expf(-ov));
                hn[r] = sg * cS[mt][r] / fmaxf(nS[mt][r], 1e-6f);
            }
            const size_t wb = ((size_t)((t + 1) & 1) * NC_ + c) * (MB_ * H_)
                            + (size_t)(mt * 16 + l4 * 4) * H_ + p * HC_ + l15;
            #pragma unroll
            for (int r = 0; r < 4; ++r) {
                float v = hn[r];
                _Float16 hi = (_Float16)v;
                _Float16 lo = (_Float16)(v - (float)hi);
                hexhi[wb + (size_t)r * H_] = hi;
                hexlo[wb + (size_t)r * H_] = lo;
                if (!isL2) {
                    const size_t ob = ((size_t)(b0g + mt * 16 + l4 * 4 + r) * T_ + t) * H_
                                    + p * HC_ + l15;
                    h1hi[ob] = hi;
                    if (useH1Lo) h1lo[ob] = lo;
                } else if (t == T_ - 1) {
                    hlast[(size_t)(b0g + mt * 16 + l4 * 4 + r) * H_ + p * HC_ + l15] = v;
                }
            }
        }

        if (lane == 0)
            __hip_atomic_store(myFlag, (unsigned)(t + 1), __ATOMIC_RELEASE,
                               __HIP_MEMORY_SCOPE_AGENT);
    }
}

#define OUT_ 26
__global__ __launch_bounds__(64)
void fc_kernel(const float* __restrict__ hlast, const float* __restrict__ fcw,
               const float* __restrict__ fcb, float* __restrict__ out)
{
    int b = blockIdx.x, o = threadIdx.x;
    if (o < OUT_) {
        const float4* hv = reinterpret_cast<const float4*>(hlast + (size_t)b * H_);
        const float4* wv = reinterpret_cast<const float4*>(fcw + (size_t)o * H_);
        float s = fcb[o];
        #pragma unroll 4
        for (int k = 0; k < H_ / 4; ++k) {
            float4 h4 = hv[k], w4 = wv[k];
            s += h4.x * w4.x + h4.y * w4.y + h4.z * w4.z + h4.w * w4.w;
        }
        out[(size_t)b * OUT_ + o] = s;
    }
}

extern "C" void kernel_launch(void* const* d_in, const int* in_sizes, int n_in,
                              void* d_out, int out_size, void* d_ws, size_t ws_size,
                              hipStream_t stream) {
    const float* x   = (const float*)d_in[0];
    const float* W0  = (const float*)d_in[1];
    const float* R0  = (const float*)d_in[2];
    const float* b0  = (const float*)d_in[3];
    const float* W1  = (const float*)d_in[4];
    const float* R1  = (const float*)d_in[5];
    const float* b1  = (const float*)d_in[6];
    const float* fcw = (const float*)d_in[7];
    const float* fcb = (const float*)d_in[8];
    float* out = (float*)d_out;

    if (ws_size < WS_NEED_SMALL) return;  // fail-visible rather than corrupt
    const int useH1Lo = (ws_size >= WS_NEED_FULL) ? 1 : 0;

    char* ws = (char*)d_ws;
    _Float16* hexhi = (_Float16*)(ws + WS_HEXHI);
    _Float16* hexlo = (_Float16*)(ws + WS_HEXLO);
    unsigned* flags = (unsigned*)(ws + WS_FLAGS);
    float*    hlast = (float*)(ws + WS_HLAST);
    _Float16* h1hi  = (_Float16*)(ws + WS_H1HI);
    _Float16* h1lo  = (_Float16*)(ws + WS_H1LO);

    hipMemsetAsync(ws, 0, WS_ZERO, stream);   // h_0 = 0 (both hex parities) + flags
    fused_slstm<<<256, 64, 0, stream>>>(x, W0, R0, b0, W1, R1, b1,
                                        hexhi, hexlo, flags, h1hi, h1lo, hlast, useH1Lo);
    fc_kernel<<<B_, 64, 0, stream>>>(hlast, fcw, fcb, out);
}